// Round 10
// baseline (149.250 us; speedup 1.0000x reference)
//
#include <hip/hip_runtime.h>
#include <hip/hip_bf16.h>
#include <math.h>

// ---------------------------------------------------------------------------
// Sketched CNN-MNIST forward, MFMA end-to-end.
// Weights AND h2 stored FRAGMENT-MAJOR so every MFMA operand load (A and B)
// is one coalesced 1 KB wave transaction from global:
//   wc*f/W3f: element (n=l15, k=quad*8+j) at [tile][lane][8]
//   h2f:      element (img, k) at [img>>4][k>>5][lane=(k>>3)&3,img&15][k&7]
// conv: 2 img/block (21.9 KB LDS -> 4 resident blocks/CU), 8 waves.
//   conv1: taps t=ki*6+kj (K=30 pad 32), even-aligned b32 A-reads, odd cols
//          via kj-shifted weights; pool picks alternating acc regs.
//   conv2: wave=(pool-row, n-half): 2 img A ds_reads + 2 B loads -> 4 MFMA.
// fc: fc1 reads A-frags + B-frags directly from global (no LDS, no barrier
//     before MFMA); h3 -> LDS; fc2 + log_softmax per-wave shuffle reduce.
// ---------------------------------------------------------------------------

typedef __attribute__((ext_vector_type(8))) short bf16x8;
typedef __attribute__((ext_vector_type(4))) float f32x4;

static __device__ inline ushort f2bfu(float v) {
    union { __hip_bfloat16 h; ushort u; } cv;
    cv.h = __float2bfloat16(v);
    return cv.u;
}

// ws layout (bytes):
//   wc1f bf16 [2 nt][64 lane][8]   frag-major      [0,       2048)
//   wc1s bf16 [2 nt][64 lane][8]   shifted         [2048,    4096)
//   wc2f bf16 [25 tap][4 nt][64 lane][8ic]         [4096,    106496)
//   W3f  bf16 [32 ntile][32 kt][64 lane][8]        [106496,  1155072)
//   h2f  bf16 [B/16][32 kt][64 lane][8]            [1155072, +B*2048)

__global__ __launch_bounds__(256)
void k_reconstruct(const float* __restrict__ w1, const float* __restrict__ w2,
                   const float* __restrict__ w3,
                   const int* __restrict__ hi1, const int* __restrict__ hi2,
                   const int* __restrict__ hi3,
                   const float* __restrict__ s1, const float* __restrict__ s2,
                   const float* __restrict__ s3,
                   __hip_bfloat16* __restrict__ wc1f,
                   __hip_bfloat16* __restrict__ wc1s,
                   __hip_bfloat16* __restrict__ wc2f,
                   __hip_bfloat16* __restrict__ W3f) {
    const int t = blockIdx.x * blockDim.x + threadIdx.x;
    bf16x8 o;
    if (t < 256) {                         // conv1 normal (t<128) / shifted
        const bool shifted = t >= 128;
        const int u = t & 127;
        const int nt = u >> 6, lane = u & 63;
        const int quad = lane >> 4, l15 = lane & 15;
        const int oc = nt * 16 + l15;
        #pragma unroll
        for (int j = 0; j < 8; ++j) {
            int tt = quad * 8 + j;
            int ki = (tt * 43) >> 8;       // tt / 6
            int kj = tt - 6 * ki;
            float v = 0.f;
            if (!shifted && ki < 5 && kj < 5) {
                int f = ki * 5 + kj;
                v = w1[oc * 128 + hi1[f]] * s1[f];
            } else if (shifted && ki < 5 && kj >= 1 && kj <= 5) {
                int f = ki * 5 + (kj - 1);
                v = w1[oc * 128 + hi1[f]] * s1[f];
            }
            o[j] = (short)f2bfu(v);
        }
        *(bf16x8*)((ushort*)(shifted ? wc1s : wc1f) + (size_t)u * 8) = o;
    } else if (t < 6656) {                 // conv2: [tap][nt][lane][8ic]
        const int u = t - 256;
        const int l15 = u & 15, quad = (u >> 4) & 3;
        const int ntA = (u >> 6) & 3, tap = u >> 8;
        const int oc = ntA * 16 + l15;
        #pragma unroll
        for (int j = 0; j < 8; ++j) {
            int ic = quad * 8 + j;
            int f = ic * 25 + tap;
            o[j] = (short)f2bfu(w2[oc * 128 + hi2[f]] * s2[f]);
        }
        *(bf16x8*)((ushort*)wc2f + (size_t)u * 8) = o;
    } else if (t < 72192) {                // fc1: [ntile][kt][lane][8]
        const int u = t - 6656;
        const int l15 = u & 15, quad = (u >> 4) & 3;
        const int kt = (u >> 6) & 31, ntile = u >> 11;
        const int n = ntile * 16 + l15;
        #pragma unroll
        for (int j = 0; j < 8; ++j) {
            int k = kt * 32 + quad * 8 + j;
            o[j] = (short)f2bfu(w3[n * 128 + hi3[k]] * s3[k]);
        }
        *(bf16x8*)((ushort*)W3f + (size_t)u * 8) = o;
    }
}

// 2 images per block, 8 waves, 4 resident blocks/CU (LDS 21.9 KB).
// h1 layout: section s = img*4 + (ic>>3); s_h1[s*1160 + pos*8 + (ic&7)].
__global__ __launch_bounds__(512, 8)
void k_conv(const float* __restrict__ x,
            const __hip_bfloat16* __restrict__ wc1f,
            const __hip_bfloat16* __restrict__ wc1s,
            const __hip_bfloat16* __restrict__ wc2f,
            const float* __restrict__ b1, const float* __restrict__ b2,
            ushort* __restrict__ h2f) {
    __shared__ __align__(16) ushort s_xb[2 * 816];     // bf16 images (+pad)
    __shared__ __align__(16) ushort s_h1[8 * 1160];    // sectioned, 18.6 KB

    const int tid = threadIdx.x;
    const int b0 = blockIdx.x * 2;
    const int wave = tid >> 6, lane = tid & 63;
    const int l15 = lane & 15, quad = lane >> 4;

    // ---- stage 2 images as bf16 (coalesced float4) ----
    {
        const float4* xg = (const float4*)(x + (size_t)b0 * 784);
        if (tid < 392) {
            float4 v = xg[tid];
            int img = tid / 196;
            int pos = (tid - img * 196) * 4;
            ushort* dst = &s_xb[img * 816 + pos];
            dst[0] = f2bfu(v.x); dst[1] = f2bfu(v.y);
            dst[2] = f2bfu(v.z); dst[3] = f2bfu(v.w);
        }
        if (tid >= 448 && tid < 512) {      // zero pad (read by pad taps, w=0)
            int u = tid - 448;
            int img = u >> 5, k = u & 31;
            s_xb[img * 816 + 784 + k] = 0;
        }
    }

    // conv1 B-fragments (frag-major: coalesced 1 KB wave loads)
    bf16x8 bw1[2], bw1s[2];
    float bb1[2];
    #pragma unroll
    for (int nt = 0; nt < 2; ++nt) {
        bw1[nt]  = *(const bf16x8*)((const ushort*)wc1f + (nt * 64 + lane) * 8);
        bw1s[nt] = *(const bf16x8*)((const ushort*)wc1s + (nt * 64 + lane) * 8);
        bb1[nt] = b1[nt * 16 + l15];
    }
    __syncthreads();

    // ---- conv1 via MFMA: wave = (img, quarter). M=576 pool-grouped, N=32 ----
    {
        const int img = wave >> 2, q = wave & 3;
        const int sub = l15 & 3;
        const ushort* srcImg = s_xb + img * 816;
        int offr[4];
        #pragma unroll
        for (int r = 0; r < 4; ++r) {
            int t = quad * 8 + 2 * r;          // even
            int row = (t * 43) >> 8;           // t / 6
            int col = t - 6 * row;             // even
            offr[r] = row * 28 + col;          // even
        }
        const int g0 = l15 >> 3, r0 = l15 & 7;
        #pragma unroll
        for (int ii = 0; ii < 9; ++ii) {
            const int i = q * 9 + ii;
            const int pb = 4 * i + (l15 >> 2);
            const int pi = (pb * 171) >> 11;   // pb / 12
            const int pj = pb - 12 * pi;
            const int base_e = (2 * pi + (sub >> 1)) * 28 + 2 * pj;   // even
            const ushort* p0 = srcImg + base_e;
            union { bf16x8 v; uint u[4]; } A;
            A.u[0] = *(const uint*)(p0 + offr[0]);
            A.u[1] = *(const uint*)(p0 + offr[1]);
            A.u[2] = *(const uint*)(p0 + offr[2]);
            A.u[3] = *(const uint*)(p0 + offr[3]);
            f32x4 z = {0.f, 0.f, 0.f, 0.f};
            f32x4 ce0 = __builtin_amdgcn_mfma_f32_16x16x32_bf16(A.v, bw1[0],  z, 0, 0, 0);
            f32x4 co0 = __builtin_amdgcn_mfma_f32_16x16x32_bf16(A.v, bw1s[0], z, 0, 0, 0);
            f32x4 ce1 = __builtin_amdgcn_mfma_f32_16x16x32_bf16(A.v, bw1[1],  z, 0, 0, 0);
            f32x4 co1 = __builtin_amdgcn_mfma_f32_16x16x32_bf16(A.v, bw1s[1], z, 0, 0, 0);
            const int pbo = 4 * i + quad;
            float m0 = fmaxf(fmaxf(ce0[0], co0[1]), fmaxf(ce0[2], co0[3]));
            float m1 = fmaxf(fmaxf(ce1[0], co1[1]), fmaxf(ce1[2], co1[3]));
            s_h1[(img * 4 + g0) * 1160 + pbo * 8 + r0]     = f2bfu(fmaxf(m0 + bb1[0], 0.f));
            s_h1[(img * 4 + 2 + g0) * 1160 + pbo * 8 + r0] = f2bfu(fmaxf(m1 + bb1[1], 0.f));
        }
    }
    __syncthreads();

    // ---- conv2: 25 tap-GEMMs, K=ic=32; wave = (pool-row, n-half), 2 images
    //      2 A ds_reads + 2 coalesced B loads -> 4 MFMA per tap ----
    const int pr = wave >> 1, nh = wave & 1;
    const int sub2 = l15 & 3;
    const int ci2 = 2 * pr + (sub2 >> 1);
    const int cj2 = 2 * (l15 >> 2) + (sub2 & 1);
    const int posBase = (ci2 * 12 + cj2) * 8;

    f32x4 acc[2][2];                       // [img][ntl]
    float bb2[2];
    #pragma unroll
    for (int ntl = 0; ntl < 2; ++ntl) {
        bb2[ntl] = b2[(nh * 2 + ntl) * 16 + l15];
        acc[0][ntl] = (f32x4){0.f, 0.f, 0.f, 0.f};
        acc[1][ntl] = (f32x4){0.f, 0.f, 0.f, 0.f};
    }

    #pragma unroll
    for (int tap = 0; tap < 25; ++tap) {
        const int ki = tap / 5, kj = tap % 5;          // compile-time
        const int off = (ki * 12 + kj) * 8;
        bf16x8 a0 = *(const bf16x8*)&s_h1[(0 * 4 + quad) * 1160 + posBase + off];
        bf16x8 a1 = *(const bf16x8*)&s_h1[(1 * 4 + quad) * 1160 + posBase + off];
        #pragma unroll
        for (int ntl = 0; ntl < 2; ++ntl) {
            bf16x8 bf = *(const bf16x8*)((const ushort*)wc2f +
                          ((tap * 4 + nh * 2 + ntl) * 64 + lane) * 8);
            acc[0][ntl] = __builtin_amdgcn_mfma_f32_16x16x32_bf16(a0, bf, acc[0][ntl], 0, 0, 0);
            acc[1][ntl] = __builtin_amdgcn_mfma_f32_16x16x32_bf16(a1, bf, acc[1][ntl], 0, 0, 0);
        }
    }

    // D rows m = quad*4+r -> (pool row = pr, pool col = quad), max over r.
    // Write h2 FRAGMENT-MAJOR: (img,k) -> [img>>4][k>>5][((k>>3)&3)*16+(img&15)][k&7]
    #pragma unroll
    for (int img = 0; img < 2; ++img) {
        const int img_g = b0 + img;
        const size_t base = (size_t)(img_g >> 4) * 16384 + (img_g & 15) * 8;
        #pragma unroll
        for (int ntl = 0; ntl < 2; ++ntl) {
            f32x4 c = acc[img][ntl];
            float m = fmaxf(fmaxf(c[0], c[1]), fmaxf(c[2], c[3]));
            float v = fmaxf(m + bb2[ntl], 0.f);
            const int k = (nh * 2 + ntl) * 256 + l15 * 16 + pr * 4 + quad;
            h2f[base + (size_t)(k >> 5) * 512 + ((k >> 3) & 3) * 128 + (k & 7)] =
                f2bfu(v);
        }
    }
}

// Fused fc1 + fc2 + log_softmax. 1024 thr = 16 waves; block = 16 images.
// fc1: wave = 32-col strip; A and B frag-major straight from global
//      (A shared across waves via L1). No LDS until the h3 epilogue.
// fc2: wave = 1 image, full-wave shuffle reduce.
__global__ __launch_bounds__(1024)
void k_fc(const ushort* __restrict__ h2f, const __hip_bfloat16* __restrict__ W3f,
          const float* __restrict__ b3, const float* __restrict__ fc2w,
          const float* __restrict__ fc2b, float* __restrict__ out) {
    __shared__ float s_h3[16 * 516];

    const int tid = threadIdx.x;
    const int wave = tid >> 6, lane = tid & 63;
    const int l15 = lane & 15, quad = lane >> 4;
    const int mBase = blockIdx.x * 16;

    f32x4 acc[2];
    acc[0] = (f32x4){0.f, 0.f, 0.f, 0.f};
    acc[1] = (f32x4){0.f, 0.f, 0.f, 0.f};

    const ushort* aP  = h2f + (size_t)blockIdx.x * 16384 + lane * 8;
    const ushort* bP0 = (const ushort*)W3f + (((size_t)(wave * 2)     * 32) * 64 + lane) * 8;
    const ushort* bP1 = (const ushort*)W3f + (((size_t)(wave * 2 + 1) * 32) * 64 + lane) * 8;
    #pragma unroll 4
    for (int kt = 0; kt < 32; ++kt) {
        bf16x8 a   = *(const bf16x8*)(aP + kt * 512);
        bf16x8 bf0 = *(const bf16x8*)(bP0 + kt * 512);
        bf16x8 bf1 = *(const bf16x8*)(bP1 + kt * 512);
        acc[0] = __builtin_amdgcn_mfma_f32_16x16x32_bf16(a, bf0, acc[0], 0, 0, 0);
        acc[1] = __builtin_amdgcn_mfma_f32_16x16x32_bf16(a, bf1, acc[1], 0, 0, 0);
    }

    #pragma unroll
    for (int ntl = 0; ntl < 2; ++ntl) {
        int col = wave * 32 + ntl * 16 + l15;
        float bb = b3[col];
        #pragma unroll
        for (int r = 0; r < 4; ++r)
            s_h3[(quad * 4 + r) * 516 + col] = fmaxf(acc[ntl][r] + bb, 0.f);
    }
    __syncthreads();

    // ---- fc2 + log_softmax: wave handles image `wave` ----
    const float* hrow = &s_h3[wave * 516];
    float4 h0 = *(const float4*)&hrow[lane * 8];
    float4 h1 = *(const float4*)&hrow[lane * 8 + 4];
    float lg[10];
    #pragma unroll
    for (int c = 0; c < 10; ++c) {
        float4 w0 = *(const float4*)&fc2w[c * 512 + lane * 8];
        float4 w1 = *(const float4*)&fc2w[c * 512 + lane * 8 + 4];
        float s = h0.x * w0.x + h0.y * w0.y + h0.z * w0.z + h0.w * w0.w
                + h1.x * w1.x + h1.y * w1.y + h1.z * w1.z + h1.w * w1.w;
        s += __shfl_down(s, 32);
        s += __shfl_down(s, 16);
        s += __shfl_down(s, 8);
        s += __shfl_down(s, 4);
        s += __shfl_down(s, 2);
        s += __shfl_down(s, 1);
        lg[c] = s;
    }
    if (lane == 0) {
        float mx = -1e30f;
        #pragma unroll
        for (int c = 0; c < 10; ++c) { lg[c] += fc2b[c]; mx = fmaxf(mx, lg[c]); }
        float sum = 0.f;
        #pragma unroll
        for (int c = 0; c < 10; ++c) sum += expf(lg[c] - mx);
        float lse = mx + logf(sum);
        #pragma unroll
        for (int c = 0; c < 10; ++c)
            out[(size_t)(mBase + wave) * 10 + c] = lg[c] - lse;
    }
}

extern "C" void kernel_launch(void* const* d_in, const int* in_sizes, int n_in,
                              void* d_out, int out_size, void* d_ws, size_t ws_size,
                              hipStream_t stream) {
    const float* x    = (const float*)d_in[0];
    const int*   hi1  = (const int*)d_in[1];
    const int*   hi2  = (const int*)d_in[2];
    const int*   hi3  = (const int*)d_in[3];
    const float* s1   = (const float*)d_in[4];
    const float* s2   = (const float*)d_in[5];
    const float* s3   = (const float*)d_in[6];
    const float* w1   = (const float*)d_in[7];
    const float* b1   = (const float*)d_in[8];
    const float* w2   = (const float*)d_in[9];
    const float* b2   = (const float*)d_in[10];
    const float* w3   = (const float*)d_in[11];
    const float* b3   = (const float*)d_in[12];
    const float* fc2w = (const float*)d_in[13];
    const float* fc2b = (const float*)d_in[14];
    float* out = (float*)d_out;

    const int B = in_sizes[0] / 784;   // 4096

    char* ws = (char*)d_ws;
    __hip_bfloat16* wc1f = (__hip_bfloat16*)(ws + 0);
    __hip_bfloat16* wc1s = (__hip_bfloat16*)(ws + 2048);
    __hip_bfloat16* wc2f = (__hip_bfloat16*)(ws + 4096);
    __hip_bfloat16* W3f  = (__hip_bfloat16*)(ws + 106496);
    ushort*         h2f  = (ushort*)(ws + 1155072);

    k_reconstruct<<<(72192 + 255) / 256, 256, 0, stream>>>(
        w1, w2, w3, hi1, hi2, hi3, s1, s2, s3, wc1f, wc1s, wc2f, W3f);
    k_conv<<<B / 2, 512, 0, stream>>>(x, wc1f, wc1s, wc2f, b1, b2, h2f);
    k_fc<<<B / 16, 1024, 0, stream>>>(h2f, W3f, b3, fc2w, fc2b, out);
}

// Round 11
// 146.234 us; speedup vs baseline: 1.0206x; 1.0206x over previous
//
#include <hip/hip_runtime.h>
#include <hip/hip_bf16.h>
#include <math.h>

// ---------------------------------------------------------------------------
// Sketched CNN-MNIST forward, MFMA end-to-end.
// Weights AND h2 stored FRAGMENT-MAJOR so every MFMA operand load (A and B)
// is one coalesced 1 KB wave transaction from global:
//   wc*f/W3f: element (n=l15, k=quad*8+j) at [tile][lane][8]
//   h2f:      element (img, k) at [img>>4][k>>5][((k>>3)&3)*16+(img&15)][k&7]
// conv: 4 img/block (R9 shape: best measured; weight-reuse/block beats
//       resident-block count — R10 regression), 8 waves, 3 blocks/CU.
// fc:   512-thr blocks (8 waves x 64-col strips), 2 blocks/CU; A/B frags
//       straight from global; fc2 + log_softmax, 2 images/wave.
// ---------------------------------------------------------------------------

typedef __attribute__((ext_vector_type(8))) short bf16x8;
typedef __attribute__((ext_vector_type(4))) float f32x4;

static __device__ inline ushort f2bfu(float v) {
    union { __hip_bfloat16 h; ushort u; } cv;
    cv.h = __float2bfloat16(v);
    return cv.u;
}

// ws layout (bytes):
//   wc1f bf16 [2 nt][64 lane][8]   frag-major      [0,       2048)
//   wc1s bf16 [2 nt][64 lane][8]   shifted         [2048,    4096)
//   wc2f bf16 [25 tap][4 nt][64 lane][8ic]         [4096,    106496)
//   W3f  bf16 [32 ntile][32 kt][64 lane][8]        [106496,  1155072)
//   h2f  bf16 [B/16][32 kt][64 lane][8]            [1155072, +B*2048)

__global__ __launch_bounds__(256)
void k_reconstruct(const float* __restrict__ w1, const float* __restrict__ w2,
                   const float* __restrict__ w3,
                   const int* __restrict__ hi1, const int* __restrict__ hi2,
                   const int* __restrict__ hi3,
                   const float* __restrict__ s1, const float* __restrict__ s2,
                   const float* __restrict__ s3,
                   __hip_bfloat16* __restrict__ wc1f,
                   __hip_bfloat16* __restrict__ wc1s,
                   __hip_bfloat16* __restrict__ wc2f,
                   __hip_bfloat16* __restrict__ W3f) {
    const int t = blockIdx.x * blockDim.x + threadIdx.x;
    bf16x8 o;
    if (t < 256) {                         // conv1 normal (t<128) / shifted
        const bool shifted = t >= 128;
        const int u = t & 127;
        const int nt = u >> 6, lane = u & 63;
        const int quad = lane >> 4, l15 = lane & 15;
        const int oc = nt * 16 + l15;
        #pragma unroll
        for (int j = 0; j < 8; ++j) {
            int tt = quad * 8 + j;
            int ki = (tt * 43) >> 8;       // tt / 6
            int kj = tt - 6 * ki;
            float v = 0.f;
            if (!shifted && ki < 5 && kj < 5) {
                int f = ki * 5 + kj;
                v = w1[oc * 128 + hi1[f]] * s1[f];
            } else if (shifted && ki < 5 && kj >= 1 && kj <= 5) {
                int f = ki * 5 + (kj - 1);
                v = w1[oc * 128 + hi1[f]] * s1[f];
            }
            o[j] = (short)f2bfu(v);
        }
        *(bf16x8*)((ushort*)(shifted ? wc1s : wc1f) + (size_t)u * 8) = o;
    } else if (t < 6656) {                 // conv2: [tap][nt][lane][8ic]
        const int u = t - 256;
        const int l15 = u & 15, quad = (u >> 4) & 3;
        const int ntA = (u >> 6) & 3, tap = u >> 8;
        const int oc = ntA * 16 + l15;
        #pragma unroll
        for (int j = 0; j < 8; ++j) {
            int ic = quad * 8 + j;
            int f = ic * 25 + tap;
            o[j] = (short)f2bfu(w2[oc * 128 + hi2[f]] * s2[f]);
        }
        *(bf16x8*)((ushort*)wc2f + (size_t)u * 8) = o;
    } else if (t < 72192) {                // fc1: [ntile][kt][lane][8]
        const int u = t - 6656;
        const int l15 = u & 15, quad = (u >> 4) & 3;
        const int kt = (u >> 6) & 31, ntile = u >> 11;
        const int n = ntile * 16 + l15;
        #pragma unroll
        for (int j = 0; j < 8; ++j) {
            int k = kt * 32 + quad * 8 + j;
            o[j] = (short)f2bfu(w3[n * 128 + hi3[k]] * s3[k]);
        }
        *(bf16x8*)((ushort*)W3f + (size_t)u * 8) = o;
    }
}

// 4 images per block, 8 waves, 3 blocks/CU (LDS 43.6 KB) — R9 shape.
// h1 layout: section s = img*4 + (ic>>3); s_h1[s*1160 + pos*8 + (ic&7)].
__global__ __launch_bounds__(512, 6)
void k_conv(const float* __restrict__ x,
            const __hip_bfloat16* __restrict__ wc1f,
            const __hip_bfloat16* __restrict__ wc1s,
            const __hip_bfloat16* __restrict__ wc2f,
            const float* __restrict__ b1, const float* __restrict__ b2,
            ushort* __restrict__ h2f) {
    __shared__ __align__(16) ushort s_xb[4 * 816];     // bf16 images (+pad)
    __shared__ __align__(16) ushort s_h1[16 * 1160];   // sectioned, 37.1 KB

    const int tid = threadIdx.x;
    const int b0 = blockIdx.x * 4;
    const int wave = tid >> 6, lane = tid & 63;
    const int l15 = lane & 15, quad = lane >> 4;

    // ---- stage 4 images as bf16 (coalesced float4) ----
    {
        const float4* xg = (const float4*)(x + (size_t)b0 * 784);
        for (int i = tid; i < 784; i += 512) {
            float4 v = xg[i];
            int img = i / 196;
            int pos = (i - img * 196) * 4;
            ushort* dst = &s_xb[img * 816 + pos];
            dst[0] = f2bfu(v.x); dst[1] = f2bfu(v.y);
            dst[2] = f2bfu(v.z); dst[3] = f2bfu(v.w);
        }
        if (tid < 128) {                    // zero pad (read by pad taps, w=0)
            int img = tid >> 5, k = tid & 31;
            s_xb[img * 816 + 784 + k] = 0;
        }
    }

    // conv1 B-fragments (frag-major: coalesced 1 KB wave loads)
    bf16x8 bw1[2], bw1s[2];
    float bb1[2];
    #pragma unroll
    for (int nt = 0; nt < 2; ++nt) {
        bw1[nt]  = *(const bf16x8*)((const ushort*)wc1f + (nt * 64 + lane) * 8);
        bw1s[nt] = *(const bf16x8*)((const ushort*)wc1s + (nt * 64 + lane) * 8);
        bb1[nt] = b1[nt * 16 + l15];
    }
    __syncthreads();

    // ---- conv1 via MFMA: wave = (img, half). M=576 pool-grouped, N=32 ----
    {
        const int img = wave >> 1, half = wave & 1;
        const int sub = l15 & 3;
        const ushort* srcImg = s_xb + img * 816;
        int offr[4];
        #pragma unroll
        for (int r = 0; r < 4; ++r) {
            int t = quad * 8 + 2 * r;          // even
            int row = (t * 43) >> 8;           // t / 6
            int col = t - 6 * row;             // even
            offr[r] = row * 28 + col;          // even
        }
        const int g0 = l15 >> 3, r0 = l15 & 7;
        #pragma unroll
        for (int ii = 0; ii < 18; ++ii) {
            const int i = half * 18 + ii;
            const int pb = 4 * i + (l15 >> 2);
            const int pi = (pb * 171) >> 11;   // pb / 12
            const int pj = pb - 12 * pi;
            const int base_e = (2 * pi + (sub >> 1)) * 28 + 2 * pj;   // even
            const ushort* p0 = srcImg + base_e;
            union { bf16x8 v; uint u[4]; } A;
            A.u[0] = *(const uint*)(p0 + offr[0]);
            A.u[1] = *(const uint*)(p0 + offr[1]);
            A.u[2] = *(const uint*)(p0 + offr[2]);
            A.u[3] = *(const uint*)(p0 + offr[3]);
            f32x4 z = {0.f, 0.f, 0.f, 0.f};
            f32x4 ce0 = __builtin_amdgcn_mfma_f32_16x16x32_bf16(A.v, bw1[0],  z, 0, 0, 0);
            f32x4 co0 = __builtin_amdgcn_mfma_f32_16x16x32_bf16(A.v, bw1s[0], z, 0, 0, 0);
            f32x4 ce1 = __builtin_amdgcn_mfma_f32_16x16x32_bf16(A.v, bw1[1],  z, 0, 0, 0);
            f32x4 co1 = __builtin_amdgcn_mfma_f32_16x16x32_bf16(A.v, bw1s[1], z, 0, 0, 0);
            const int pbo = 4 * i + quad;
            float m0 = fmaxf(fmaxf(ce0[0], co0[1]), fmaxf(ce0[2], co0[3]));
            float m1 = fmaxf(fmaxf(ce1[0], co1[1]), fmaxf(ce1[2], co1[3]));
            s_h1[(img * 4 + g0) * 1160 + pbo * 8 + r0]     = f2bfu(fmaxf(m0 + bb1[0], 0.f));
            s_h1[(img * 4 + 2 + g0) * 1160 + pbo * 8 + r0] = f2bfu(fmaxf(m1 + bb1[1], 0.f));
        }
    }
    __syncthreads();

    // ---- conv2: 25 tap-GEMMs, K=ic=32; wave = (pool-row, n-half), 4 images
    //      4 A ds_reads + 2 coalesced B loads -> 8 MFMA per tap ----
    const int pr = wave >> 1, nh = wave & 1;
    const int sub2 = l15 & 3;
    const int ci2 = 2 * pr + (sub2 >> 1);
    const int cj2 = 2 * (l15 >> 2) + (sub2 & 1);
    const int posBase = (ci2 * 12 + cj2) * 8;

    f32x4 acc[4][2];                       // [img][ntl]
    float bb2[2];
    #pragma unroll
    for (int ntl = 0; ntl < 2; ++ntl) {
        bb2[ntl] = b2[(nh * 2 + ntl) * 16 + l15];
        #pragma unroll
        for (int img = 0; img < 4; ++img)
            acc[img][ntl] = (f32x4){0.f, 0.f, 0.f, 0.f};
    }

    #pragma unroll
    for (int tap = 0; tap < 25; ++tap) {
        const int ki = tap / 5, kj = tap % 5;          // compile-time
        const int off = (ki * 12 + kj) * 8;
        bf16x8 a[4];
        #pragma unroll
        for (int img = 0; img < 4; ++img)
            a[img] = *(const bf16x8*)&s_h1[(img * 4 + quad) * 1160 + posBase + off];
        #pragma unroll
        for (int ntl = 0; ntl < 2; ++ntl) {
            bf16x8 bf = *(const bf16x8*)((const ushort*)wc2f +
                          ((tap * 4 + nh * 2 + ntl) * 64 + lane) * 8);
            #pragma unroll
            for (int img = 0; img < 4; ++img)
                acc[img][ntl] = __builtin_amdgcn_mfma_f32_16x16x32_bf16(
                    a[img], bf, acc[img][ntl], 0, 0, 0);
        }
    }

    // D rows m = quad*4+r -> (pool row = pr, pool col = quad), max over r.
    // Write h2 FRAGMENT-MAJOR.
    #pragma unroll
    for (int img = 0; img < 4; ++img) {
        const int img_g = b0 + img;
        const size_t base = (size_t)(img_g >> 4) * 16384 + (img_g & 15) * 8;
        #pragma unroll
        for (int ntl = 0; ntl < 2; ++ntl) {
            f32x4 c = acc[img][ntl];
            float m = fmaxf(fmaxf(c[0], c[1]), fmaxf(c[2], c[3]));
            float v = fmaxf(m + bb2[ntl], 0.f);
            const int k = (nh * 2 + ntl) * 256 + l15 * 16 + pr * 4 + quad;
            h2f[base + (size_t)(k >> 5) * 512 + ((k >> 3) & 3) * 128 + (k & 7)] =
                f2bfu(v);
        }
    }
}

// Fused fc1 + fc2 + log_softmax. 512 thr = 8 waves; block = 16 images;
// 2 blocks/CU. fc1: wave = 64-col strip (4 n-tiles), A/B frag-major from
// global (A L1-broadcast across waves). fc2: wave = 2 images, shuffle reduce.
__global__ __launch_bounds__(512, 4)
void k_fc(const ushort* __restrict__ h2f, const __hip_bfloat16* __restrict__ W3f,
          const float* __restrict__ b3, const float* __restrict__ fc2w,
          const float* __restrict__ fc2b, float* __restrict__ out) {
    __shared__ float s_h3[16 * 516];

    const int tid = threadIdx.x;
    const int wave = tid >> 6, lane = tid & 63;
    const int l15 = lane & 15, quad = lane >> 4;
    const int mBase = blockIdx.x * 16;

    f32x4 acc[4];
    #pragma unroll
    for (int ntl = 0; ntl < 4; ++ntl) acc[ntl] = (f32x4){0.f, 0.f, 0.f, 0.f};

    const ushort* aP = h2f + (size_t)blockIdx.x * 16384 + lane * 8;
    const ushort* bP[4];
    #pragma unroll
    for (int ntl = 0; ntl < 4; ++ntl)
        bP[ntl] = (const ushort*)W3f + ((size_t)(wave * 4 + ntl) * 2048 + lane) * 8;

    #pragma unroll 2
    for (int kt = 0; kt < 32; ++kt) {
        bf16x8 a = *(const bf16x8*)(aP + kt * 512);
        #pragma unroll
        for (int ntl = 0; ntl < 4; ++ntl) {
            bf16x8 bf = *(const bf16x8*)(bP[ntl] + kt * 512);
            acc[ntl] = __builtin_amdgcn_mfma_f32_16x16x32_bf16(a, bf, acc[ntl], 0, 0, 0);
        }
    }

    #pragma unroll
    for (int ntl = 0; ntl < 4; ++ntl) {
        int col = wave * 64 + ntl * 16 + l15;
        float bb = b3[col];
        #pragma unroll
        for (int r = 0; r < 4; ++r)
            s_h3[(quad * 4 + r) * 516 + col] = fmaxf(acc[ntl][r] + bb, 0.f);
    }
    __syncthreads();

    // ---- fc2 + log_softmax: wave handles images 2*wave, 2*wave+1 ----
    #pragma unroll
    for (int i2 = 0; i2 < 2; ++i2) {
        const int m = wave * 2 + i2;
        const float* hrow = &s_h3[m * 516];
        float4 h0 = *(const float4*)&hrow[lane * 8];
        float4 h1 = *(const float4*)&hrow[lane * 8 + 4];
        float lg[10];
        #pragma unroll
        for (int c = 0; c < 10; ++c) {
            float4 w0 = *(const float4*)&fc2w[c * 512 + lane * 8];
            float4 w1 = *(const float4*)&fc2w[c * 512 + lane * 8 + 4];
            float s = h0.x * w0.x + h0.y * w0.y + h0.z * w0.z + h0.w * w0.w
                    + h1.x * w1.x + h1.y * w1.y + h1.z * w1.z + h1.w * w1.w;
            s += __shfl_down(s, 32);
            s += __shfl_down(s, 16);
            s += __shfl_down(s, 8);
            s += __shfl_down(s, 4);
            s += __shfl_down(s, 2);
            s += __shfl_down(s, 1);
            lg[c] = s;
        }
        if (lane == 0) {
            float mx = -1e30f;
            #pragma unroll
            for (int c = 0; c < 10; ++c) { lg[c] += fc2b[c]; mx = fmaxf(mx, lg[c]); }
            float sum = 0.f;
            #pragma unroll
            for (int c = 0; c < 10; ++c) sum += expf(lg[c] - mx);
            float lse = mx + logf(sum);
            #pragma unroll
            for (int c = 0; c < 10; ++c)
                out[(size_t)(mBase + m) * 10 + c] = lg[c] - lse;
        }
    }
}

extern "C" void kernel_launch(void* const* d_in, const int* in_sizes, int n_in,
                              void* d_out, int out_size, void* d_ws, size_t ws_size,
                              hipStream_t stream) {
    const float* x    = (const float*)d_in[0];
    const int*   hi1  = (const int*)d_in[1];
    const int*   hi2  = (const int*)d_in[2];
    const int*   hi3  = (const int*)d_in[3];
    const float* s1   = (const float*)d_in[4];
    const float* s2   = (const float*)d_in[5];
    const float* s3   = (const float*)d_in[6];
    const float* w1   = (const float*)d_in[7];
    const float* b1   = (const float*)d_in[8];
    const float* w2   = (const float*)d_in[9];
    const float* b2   = (const float*)d_in[10];
    const float* w3   = (const float*)d_in[11];
    const float* b3   = (const float*)d_in[12];
    const float* fc2w = (const float*)d_in[13];
    const float* fc2b = (const float*)d_in[14];
    float* out = (float*)d_out;

    const int B = in_sizes[0] / 784;   // 4096

    char* ws = (char*)d_ws;
    __hip_bfloat16* wc1f = (__hip_bfloat16*)(ws + 0);
    __hip_bfloat16* wc1s = (__hip_bfloat16*)(ws + 2048);
    __hip_bfloat16* wc2f = (__hip_bfloat16*)(ws + 4096);
    __hip_bfloat16* W3f  = (__hip_bfloat16*)(ws + 106496);
    ushort*         h2f  = (ushort*)(ws + 1155072);

    k_reconstruct<<<(72192 + 255) / 256, 256, 0, stream>>>(
        w1, w2, w3, hi1, hi2, hi3, s1, s2, s3, wc1f, wc1s, wc2f, W3f);
    k_conv<<<B / 4, 512, 0, stream>>>(x, wc1f, wc1s, wc2f, b1, b2, h2f);
    k_fc<<<B / 16, 512, 0, stream>>>(h2f, W3f, b3, fc2w, fc2b, out);
}

// Round 12
// 142.026 us; speedup vs baseline: 1.0509x; 1.0296x over previous
//
#include <hip/hip_runtime.h>
#include <hip/hip_bf16.h>
#include <math.h>

// ---------------------------------------------------------------------------
// Sketched CNN-MNIST forward, MFMA end-to-end.
// Weights AND h2 stored FRAGMENT-MAJOR so every MFMA operand load is one
// coalesced 1 KB wave transaction from global:
//   wc*f/W3f: element (n=l15, k=quad*8+j) at [tile][lane][8]
//   h2f:      element (img, k) at [img>>4][k>>5][((k>>3)&3)*16+(img&15)][k&7]
// conv: 4 img/block, 8 waves, 3 blocks/CU (R9/R11 shape — best measured).
//   conv1: image in LDS at row stride 30 ushorts (odd uint stride 15 ->
//          bank-spread, kills the 4-way gather conflicts of stride 28).
//   conv2: wave=(pool-row, n-half): 4 img A ds_reads + 2 B loads -> 8 MFMA.
// fc: R9 structure (best measured): 1024 thr, block = 16 images; stage the
//     32 KB h2f tile into LDS once, 16 waves x 32-col strips read A-frags
//     from LDS + B-frags from global; fused fc2 + log_softmax, 1 img/wave.
// ---------------------------------------------------------------------------

typedef __attribute__((ext_vector_type(8))) short bf16x8;
typedef __attribute__((ext_vector_type(4))) float f32x4;

static __device__ inline ushort f2bfu(float v) {
    union { __hip_bfloat16 h; ushort u; } cv;
    cv.h = __float2bfloat16(v);
    return cv.u;
}

// ws layout (bytes):
//   wc1f bf16 [2 nt][64 lane][8]   frag-major      [0,       2048)
//   wc1s bf16 [2 nt][64 lane][8]   shifted         [2048,    4096)
//   wc2f bf16 [25 tap][4 nt][64 lane][8ic]         [4096,    106496)
//   W3f  bf16 [32 ntile][32 kt][64 lane][8]        [106496,  1155072)
//   h2f  bf16 [B/16][32 kt][64 lane][8]            [1155072, +B*2048)

__global__ __launch_bounds__(256)
void k_reconstruct(const float* __restrict__ w1, const float* __restrict__ w2,
                   const float* __restrict__ w3,
                   const int* __restrict__ hi1, const int* __restrict__ hi2,
                   const int* __restrict__ hi3,
                   const float* __restrict__ s1, const float* __restrict__ s2,
                   const float* __restrict__ s3,
                   __hip_bfloat16* __restrict__ wc1f,
                   __hip_bfloat16* __restrict__ wc1s,
                   __hip_bfloat16* __restrict__ wc2f,
                   __hip_bfloat16* __restrict__ W3f) {
    const int t = blockIdx.x * blockDim.x + threadIdx.x;
    bf16x8 o;
    if (t < 256) {                         // conv1 normal (t<128) / shifted
        const bool shifted = t >= 128;
        const int u = t & 127;
        const int nt = u >> 6, lane = u & 63;
        const int quad = lane >> 4, l15 = lane & 15;
        const int oc = nt * 16 + l15;
        #pragma unroll
        for (int j = 0; j < 8; ++j) {
            int tt = quad * 8 + j;
            int ki = (tt * 43) >> 8;       // tt / 6
            int kj = tt - 6 * ki;
            float v = 0.f;
            if (!shifted && ki < 5 && kj < 5) {
                int f = ki * 5 + kj;
                v = w1[oc * 128 + hi1[f]] * s1[f];
            } else if (shifted && ki < 5 && kj >= 1 && kj <= 5) {
                int f = ki * 5 + (kj - 1);
                v = w1[oc * 128 + hi1[f]] * s1[f];
            }
            o[j] = (short)f2bfu(v);
        }
        *(bf16x8*)((ushort*)(shifted ? wc1s : wc1f) + (size_t)u * 8) = o;
    } else if (t < 6656) {                 // conv2: [tap][nt][lane][8ic]
        const int u = t - 256;
        const int l15 = u & 15, quad = (u >> 4) & 3;
        const int ntA = (u >> 6) & 3, tap = u >> 8;
        const int oc = ntA * 16 + l15;
        #pragma unroll
        for (int j = 0; j < 8; ++j) {
            int ic = quad * 8 + j;
            int f = ic * 25 + tap;
            o[j] = (short)f2bfu(w2[oc * 128 + hi2[f]] * s2[f]);
        }
        *(bf16x8*)((ushort*)wc2f + (size_t)u * 8) = o;
    } else if (t < 72192) {                // fc1: [ntile][kt][lane][8]
        const int u = t - 6656;
        const int l15 = u & 15, quad = (u >> 4) & 3;
        const int kt = (u >> 6) & 31, ntile = u >> 11;
        const int n = ntile * 16 + l15;
        #pragma unroll
        for (int j = 0; j < 8; ++j) {
            int k = kt * 32 + quad * 8 + j;
            o[j] = (short)f2bfu(w3[n * 128 + hi3[k]] * s3[k]);
        }
        *(bf16x8*)((ushort*)W3f + (size_t)u * 8) = o;
    }
}

// 4 images per block, 8 waves, 3 blocks/CU.
// s_xb: row stride 30 ushorts (15 uints, odd -> bank spread); image stride 880.
// h1 layout: section s = img*4 + (ic>>3); s_h1[s*1160 + pos*8 + (ic&7)].
__global__ __launch_bounds__(512, 6)
void k_conv(const float* __restrict__ x,
            const __hip_bfloat16* __restrict__ wc1f,
            const __hip_bfloat16* __restrict__ wc1s,
            const __hip_bfloat16* __restrict__ wc2f,
            const float* __restrict__ b1, const float* __restrict__ b2,
            ushort* __restrict__ h2f) {
    __shared__ __align__(16) ushort s_xb[4 * 880];     // bf16 images, stride 30
    __shared__ __align__(16) ushort s_h1[16 * 1160];   // sectioned, 37.1 KB

    const int tid = threadIdx.x;
    const int b0 = blockIdx.x * 4;
    const int wave = tid >> 6, lane = tid & 63;
    const int l15 = lane & 15, quad = lane >> 4;

    // ---- stage 4 images as bf16 at row stride 30 (coalesced float4 in) ----
    {
        const float4* xg = (const float4*)(x + (size_t)b0 * 784);
        for (int i = tid; i < 784; i += 512) {
            float4 v = xg[i];
            int img = i / 196;
            int pos = (i - img * 196) * 4;
            int row = pos / 28, col = pos - row * 28;   // col multiple of 4, <=24
            ushort* dst = &s_xb[img * 880 + row * 30 + col];
            dst[0] = f2bfu(v.x); dst[1] = f2bfu(v.y);
            dst[2] = f2bfu(v.z); dst[3] = f2bfu(v.w);
        }
        if (tid < 160) {                    // zero row>=28 region (pad taps, w=0)
            int img = tid / 40, k = tid - 40 * (tid / 40);
            s_xb[img * 880 + 840 + k] = 0;
        }
    }

    // conv1 B-fragments (frag-major: coalesced 1 KB wave loads)
    bf16x8 bw1[2], bw1s[2];
    float bb1[2];
    #pragma unroll
    for (int nt = 0; nt < 2; ++nt) {
        bw1[nt]  = *(const bf16x8*)((const ushort*)wc1f + (nt * 64 + lane) * 8);
        bw1s[nt] = *(const bf16x8*)((const ushort*)wc1s + (nt * 64 + lane) * 8);
        bb1[nt] = b1[nt * 16 + l15];
    }
    __syncthreads();

    // ---- conv1 via MFMA: wave = (img, half). M=576 pool-grouped, N=32 ----
    {
        const int img = wave >> 1, half = wave & 1;
        const int sub = l15 & 3;
        const ushort* srcImg = s_xb + img * 880;
        int offr[4];
        #pragma unroll
        for (int r = 0; r < 4; ++r) {
            int t = quad * 8 + 2 * r;          // even
            int row = (t * 43) >> 8;           // t / 6
            int col = t - 6 * row;             // even
            offr[r] = row * 30 + col;          // even (stride 30)
        }
        const int g0 = l15 >> 3, r0 = l15 & 7;
        #pragma unroll
        for (int ii = 0; ii < 18; ++ii) {
            const int i = half * 18 + ii;
            const int pb = 4 * i + (l15 >> 2);
            const int pi = (pb * 171) >> 11;   // pb / 12
            const int pj = pb - 12 * pi;
            const int base_e = (2 * pi + (sub >> 1)) * 30 + 2 * pj;   // even
            const ushort* p0 = srcImg + base_e;
            union { bf16x8 v; uint u[4]; } A;
            A.u[0] = *(const uint*)(p0 + offr[0]);
            A.u[1] = *(const uint*)(p0 + offr[1]);
            A.u[2] = *(const uint*)(p0 + offr[2]);
            A.u[3] = *(const uint*)(p0 + offr[3]);
            f32x4 z = {0.f, 0.f, 0.f, 0.f};
            f32x4 ce0 = __builtin_amdgcn_mfma_f32_16x16x32_bf16(A.v, bw1[0],  z, 0, 0, 0);
            f32x4 co0 = __builtin_amdgcn_mfma_f32_16x16x32_bf16(A.v, bw1s[0], z, 0, 0, 0);
            f32x4 ce1 = __builtin_amdgcn_mfma_f32_16x16x32_bf16(A.v, bw1[1],  z, 0, 0, 0);
            f32x4 co1 = __builtin_amdgcn_mfma_f32_16x16x32_bf16(A.v, bw1s[1], z, 0, 0, 0);
            const int pbo = 4 * i + quad;
            float m0 = fmaxf(fmaxf(ce0[0], co0[1]), fmaxf(ce0[2], co0[3]));
            float m1 = fmaxf(fmaxf(ce1[0], co1[1]), fmaxf(ce1[2], co1[3]));
            s_h1[(img * 4 + g0) * 1160 + pbo * 8 + r0]     = f2bfu(fmaxf(m0 + bb1[0], 0.f));
            s_h1[(img * 4 + 2 + g0) * 1160 + pbo * 8 + r0] = f2bfu(fmaxf(m1 + bb1[1], 0.f));
        }
    }
    __syncthreads();

    // ---- conv2: 25 tap-GEMMs, K=ic=32; wave = (pool-row, n-half), 4 images
    //      4 A ds_reads + 2 coalesced B loads -> 8 MFMA per tap ----
    const int pr = wave >> 1, nh = wave & 1;
    const int sub2 = l15 & 3;
    const int ci2 = 2 * pr + (sub2 >> 1);
    const int cj2 = 2 * (l15 >> 2) + (sub2 & 1);
    const int posBase = (ci2 * 12 + cj2) * 8;

    f32x4 acc[4][2];                       // [img][ntl]
    float bb2[2];
    #pragma unroll
    for (int ntl = 0; ntl < 2; ++ntl) {
        bb2[ntl] = b2[(nh * 2 + ntl) * 16 + l15];
        #pragma unroll
        for (int img = 0; img < 4; ++img)
            acc[img][ntl] = (f32x4){0.f, 0.f, 0.f, 0.f};
    }

    #pragma unroll
    for (int tap = 0; tap < 25; ++tap) {
        const int ki = tap / 5, kj = tap % 5;          // compile-time
        const int off = (ki * 12 + kj) * 8;
        bf16x8 a[4];
        #pragma unroll
        for (int img = 0; img < 4; ++img)
            a[img] = *(const bf16x8*)&s_h1[(img * 4 + quad) * 1160 + posBase + off];
        #pragma unroll
        for (int ntl = 0; ntl < 2; ++ntl) {
            bf16x8 bf = *(const bf16x8*)((const ushort*)wc2f +
                          ((tap * 4 + nh * 2 + ntl) * 64 + lane) * 8);
            #pragma unroll
            for (int img = 0; img < 4; ++img)
                acc[img][ntl] = __builtin_amdgcn_mfma_f32_16x16x32_bf16(
                    a[img], bf, acc[img][ntl], 0, 0, 0);
        }
    }

    // D rows m = quad*4+r -> (pool row = pr, pool col = quad), max over r.
    // Write h2 FRAGMENT-MAJOR.
    #pragma unroll
    for (int img = 0; img < 4; ++img) {
        const int img_g = b0 + img;
        const size_t base = (size_t)(img_g >> 4) * 16384 + (img_g & 15) * 8;
        #pragma unroll
        for (int ntl = 0; ntl < 2; ++ntl) {
            f32x4 c = acc[img][ntl];
            float m = fmaxf(fmaxf(c[0], c[1]), fmaxf(c[2], c[3]));
            float v = fmaxf(m + bb2[ntl], 0.f);
            const int k = (nh * 2 + ntl) * 256 + l15 * 16 + pr * 4 + quad;
            h2f[base + (size_t)(k >> 5) * 512 + ((k >> 3) & 3) * 128 + (k & 7)] =
                f2bfu(v);
        }
    }
}

// Fused fc1 + fc2 + log_softmax. 1024 thr = 16 waves; block = 16 images.
// Stage the 32 KB frag-major h2f tile into LDS once; fc1: wave = 32-col strip
// (2 chains), A-frags from LDS, B-frags coalesced from global.
// fc2: wave = 1 image, full-wave shuffle reduce.  (R9 structure — best measured.)
__global__ __launch_bounds__(1024)
void k_fc(const ushort* __restrict__ h2f, const __hip_bfloat16* __restrict__ W3f,
          const float* __restrict__ b3, const float* __restrict__ fc2w,
          const float* __restrict__ fc2b, float* __restrict__ out) {
    __shared__ __align__(16) ushort s_A[16384];   // 32 KB frag-major A tile
    __shared__ float s_h3[16 * 516];

    const int tid = threadIdx.x;
    const int wave = tid >> 6, lane = tid & 63;
    const int l15 = lane & 15, quad = lane >> 4;
    const int mBase = blockIdx.x * 16;

    // stage A tile (contiguous 32 KB, fully coalesced)
    {
        const uint4* g = (const uint4*)(h2f + (size_t)blockIdx.x * 16384);
        uint4* d = (uint4*)s_A;
        d[tid] = g[tid];
        d[tid + 1024] = g[tid + 1024];
    }
    __syncthreads();

    f32x4 acc[2];
    acc[0] = (f32x4){0.f, 0.f, 0.f, 0.f};
    acc[1] = (f32x4){0.f, 0.f, 0.f, 0.f};

    const ushort* aP  = s_A + lane * 8;
    const ushort* bP0 = (const ushort*)W3f + ((size_t)(wave * 2)     * 16384 + lane * 8);
    const ushort* bP1 = (const ushort*)W3f + ((size_t)(wave * 2 + 1) * 16384 + lane * 8);
    #pragma unroll 4
    for (int kt = 0; kt < 32; ++kt) {
        bf16x8 a   = *(const bf16x8*)(aP + kt * 512);
        bf16x8 bf0 = *(const bf16x8*)(bP0 + kt * 512);
        bf16x8 bf1 = *(const bf16x8*)(bP1 + kt * 512);
        acc[0] = __builtin_amdgcn_mfma_f32_16x16x32_bf16(a, bf0, acc[0], 0, 0, 0);
        acc[1] = __builtin_amdgcn_mfma_f32_16x16x32_bf16(a, bf1, acc[1], 0, 0, 0);
    }

    #pragma unroll
    for (int ntl = 0; ntl < 2; ++ntl) {
        int col = wave * 32 + ntl * 16 + l15;
        float bb = b3[col];
        #pragma unroll
        for (int r = 0; r < 4; ++r)
            s_h3[(quad * 4 + r) * 516 + col] = fmaxf(acc[ntl][r] + bb, 0.f);
    }
    __syncthreads();

    // ---- fc2 + log_softmax: wave handles image `wave` ----
    const float* hrow = &s_h3[wave * 516];
    float4 h0 = *(const float4*)&hrow[lane * 8];
    float4 h1 = *(const float4*)&hrow[lane * 8 + 4];
    float lg[10];
    #pragma unroll
    for (int c = 0; c < 10; ++c) {
        float4 w0 = *(const float4*)&fc2w[c * 512 + lane * 8];
        float4 w1 = *(const float4*)&fc2w[c * 512 + lane * 8 + 4];
        float s = h0.x * w0.x + h0.y * w0.y + h0.z * w0.z + h0.w * w0.w
                + h1.x * w1.x + h1.y * w1.y + h1.z * w1.z + h1.w * w1.w;
        s += __shfl_down(s, 32);
        s += __shfl_down(s, 16);
        s += __shfl_down(s, 8);
        s += __shfl_down(s, 4);
        s += __shfl_down(s, 2);
        s += __shfl_down(s, 1);
        lg[c] = s;
    }
    if (lane == 0) {
        float mx = -1e30f;
        #pragma unroll
        for (int c = 0; c < 10; ++c) { lg[c] += fc2b[c]; mx = fmaxf(mx, lg[c]); }
        float sum = 0.f;
        #pragma unroll
        for (int c = 0; c < 10; ++c) sum += expf(lg[c] - mx);
        float lse = mx + logf(sum);
        #pragma unroll
        for (int c = 0; c < 10; ++c)
            out[(size_t)(mBase + wave) * 10 + c] = lg[c] - lse;
    }
}

extern "C" void kernel_launch(void* const* d_in, const int* in_sizes, int n_in,
                              void* d_out, int out_size, void* d_ws, size_t ws_size,
                              hipStream_t stream) {
    const float* x    = (const float*)d_in[0];
    const int*   hi1  = (const int*)d_in[1];
    const int*   hi2  = (const int*)d_in[2];
    const int*   hi3  = (const int*)d_in[3];
    const float* s1   = (const float*)d_in[4];
    const float* s2   = (const float*)d_in[5];
    const float* s3   = (const float*)d_in[6];
    const float* w1   = (const float*)d_in[7];
    const float* b1   = (const float*)d_in[8];
    const float* w2   = (const float*)d_in[9];
    const float* b2   = (const float*)d_in[10];
    const float* w3   = (const float*)d_in[11];
    const float* b3   = (const float*)d_in[12];
    const float* fc2w = (const float*)d_in[13];
    const float* fc2b = (const float*)d_in[14];
    float* out = (float*)d_out;

    const int B = in_sizes[0] / 784;   // 4096

    char* ws = (char*)d_ws;
    __hip_bfloat16* wc1f = (__hip_bfloat16*)(ws + 0);
    __hip_bfloat16* wc1s = (__hip_bfloat16*)(ws + 2048);
    __hip_bfloat16* wc2f = (__hip_bfloat16*)(ws + 4096);
    __hip_bfloat16* W3f  = (__hip_bfloat16*)(ws + 106496);
    ushort*         h2f  = (ushort*)(ws + 1155072);

    k_reconstruct<<<(72192 + 255) / 256, 256, 0, stream>>>(
        w1, w2, w3, hi1, hi2, hi3, s1, s2, s3, wc1f, wc1s, wc2f, W3f);
    k_conv<<<B / 4, 512, 0, stream>>>(x, wc1f, wc1s, wc2f, b1, b2, h2f);
    k_fc<<<B / 16, 1024, 0, stream>>>(h2f, W3f, b3, fc2w, fc2b, out);
}